// Round 10
// baseline (489.428 us; speedup 1.0000x reference)
//
#include <hip/hip_runtime.h>

// LSTM B=2048, T=1024, H=50. Round 10: 4-wave block, 1 pair/lane, no copies.
//
// grid=512 (BW=4 batches/block, 2 independent blocks/CU), block=256 = 4 waves
// (1 wave/SIMD: no cross-wave issue serialization at the barrier).
// Wave w owns tiles T=4w+cp (cp=0..3) of the 13 permuted gate-row tiles
// (rows n'=4j+g); wave 3 computes only tile 12 (13-15 are pad, skipped).
// D-column n maps to batch n&3, copy-group cp=n>>2 -> lane (kq,L15) takes
// acc[cp] and owns pair (unit j=16w+4cp+kq, batch b=L15&3): one f16 h-write,
// B-fragments read h ONCE per batch row (same-address lanes broadcast free).
// hb row stride 80 f16 (160 B = 40 words): b128 reads exactly 2-way = free.
// A = scaled W' single f16 in VGPRs (validated R9: absmax unchanged 4.88e-4).
//   Row scale: i,f,o x -log2(e); g x +2log2(e) -> exp2-only activations.
//   K slots: 0-49 W_hh | 50 wih_hi(B=x_hi) | 51 wih_hi(B=x_lo)
//            52 wih_lo(B=x_hi) | 53 bias_hi(B=1) | 54 bias_lo(B=1).
// Per step/wave: 2 ds_read_b128 + 8 MFMA (w3: 2) + ~12 cndmask + 10 trans +
// ~20 VALU + 1 ds_write_b16 + 1 barrier.

#define H     50
#define TT    1024
#define BATCH 2048
#define BW    4
#define NTHR  256     // 4 waves
#define KP    80      // f16 per hb row: 160 B = 40 words -> 2-way banks (free)
#define KX_HI 50
#define KX_LO 51
#define KX_H2 52
#define KB_HI 53
#define KB_LO 54

typedef float    f32x4 __attribute__((ext_vector_type(4)));
typedef _Float16 f16x8 __attribute__((ext_vector_type(8)));

__global__ __launch_bounds__(NTHR, 2) void lstm_kernel(
    const float* __restrict__ x,      // [B, T]
    const float* __restrict__ W_ih,   // [200]
    const float* __restrict__ W_hh,   // [200, 50]
    const float* __restrict__ b_ih,   // [200]
    const float* __restrict__ b_hh,   // [200]
    const float* __restrict__ W_lin,  // [50]
    const float* __restrict__ b_lin,  // [1]
    float* __restrict__ out)          // [B]
{
    __shared__ _Float16 hb[2][BW][KP];   // h^T + x/bias slots, double-buffered
    __shared__ float    redH[H][BW];     // head reduction

    const int tid  = threadIdx.x;
    const int wave = tid >> 6;
    const int lane = tid & 63;
    const int L15  = lane & 15;
    const int kq   = lane >> 4;
    const int bl   = L15 & 3;            // batch of this lane
    const int cp   = L15 >> 2;           // copy-group -> tile select
    const int b0   = blockIdx.x * BW;

    const float LOG2E  = 1.4426950408889634f;
    const float LOG2E2 = 2.8853900817779268f;

    // ---- A fragments: scaled permuted W' rows, single f16, in VGPRs ----
    // tile i: T=4*wave+i; A[m=L15][k=kf*32+kq*8+e], global row 16T+L15 = 4j+g
    f16x8 A[4][2];
    #pragma unroll
    for (int i = 0; i < 4; ++i) {
        const int T  = 4 * wave + i;
        const int m  = T * 16 + L15;
        const int jm = m >> 2, gm = m & 3;
        const bool v = (jm < H);            // T>=13 rows are all pad
        const float s = (gm == 2) ? LOG2E2 : -LOG2E;
        float swih = 0.f, sbias = 0.f;
        if (v) {
            swih  = s * W_ih[gm * H + jm];
            sbias = s * (b_ih[gm * H + jm] + b_hh[gm * H + jm]);
        }
        const _Float16 whi = (_Float16)swih;
        const _Float16 wlo = (_Float16)(swih - (float)whi);
        const _Float16 bhi = (_Float16)sbias;
        const _Float16 blo = (_Float16)(sbias - (float)bhi);
        #pragma unroll
        for (int kf = 0; kf < 2; ++kf) {
            f16x8 vv;
            #pragma unroll
            for (int e = 0; e < 8; ++e) {
                const int k = kf * 32 + kq * 8 + e;
                _Float16 val = (_Float16)0.f;
                if (v) {
                    if (k < H)            val = (_Float16)(s * W_hh[(gm * H + jm) * H + k]);
                    else if (k == KX_HI)  val = whi;
                    else if (k == KX_LO)  val = whi;
                    else if (k == KX_H2)  val = wlo;
                    else if (k == KB_HI)  val = bhi;
                    else if (k == KB_LO)  val = blo;
                }
                vv[e] = val;
            }
            A[i][kf] = vv;
        }
    }

    // ---- this lane's pair ----
    const int  j  = 16 * wave + 4 * cp + kq;
    const bool jv = (j < H);
    const float wlin = jv ? W_lin[j] : 0.f;

    // ---- init LDS ----
    for (int i = tid; i < 2 * BW * KP; i += NTHR)
        ((_Float16*)hb)[i] = (_Float16)0.f;
    __syncthreads();
    if (tid < 8) {                        // bias-one slots, both buffers
        hb[tid >> 2][tid & 3][KB_HI] = (_Float16)1.0f;
        hb[tid >> 2][tid & 3][KB_LO] = (_Float16)1.0f;
    } else if (tid < 12) {                // x(t=0) slots, buffer 0
        const int bb = tid - 8;
        const float xv = x[(size_t)(b0 + bb) * TT];
        const _Float16 xh = (_Float16)xv;
        hb[0][bb][KX_HI] = xh;
        hb[0][bb][KX_LO] = (_Float16)(xv - (float)xh);
        hb[0][bb][KX_H2] = xh;
    }

    // ---- x prefetch (wave 0 lanes; only L15<4,kq<3 consume) ----
    const float* xrow = x + (size_t)(b0 + bl) * TT;
    float4 xq = {0,0,0,0}, xq2 = {0,0,0,0};
    if (wave == 0) {
        xq  = *(const float4*)(xrow);
        xq2 = *(const float4*)(xrow + 4);
    }

    float c = 0.f, hlast = 0.f;
    __syncthreads();

    for (int t = 0; t < TT; ++t) {
        // ---- B fragments: broadcast read of batch row bl ----
        const _Float16* hp = &hb[t & 1][bl][0];
        f16x8 B0 = *(const f16x8*)(hp + kq * 8);        // k 0..31
        f16x8 B1 = *(const f16x8*)(hp + 32 + kq * 8);   // k 32..63

        // ---- MFMA: wave<3 -> 4 tiles, wave 3 -> tile 12 only ----
        const f32x4 z = {0.f, 0.f, 0.f, 0.f};
        f32x4 a0, a1 = z, a2 = z, a3 = z;
        a0 = __builtin_amdgcn_mfma_f32_16x16x32_f16(A[0][0], B0, z, 0, 0, 0);
        a0 = __builtin_amdgcn_mfma_f32_16x16x32_f16(A[0][1], B1, a0, 0, 0, 0);
        if (wave != 3) {
            a1 = __builtin_amdgcn_mfma_f32_16x16x32_f16(A[1][0], B0, z, 0, 0, 0);
            a2 = __builtin_amdgcn_mfma_f32_16x16x32_f16(A[2][0], B0, z, 0, 0, 0);
            a3 = __builtin_amdgcn_mfma_f32_16x16x32_f16(A[3][0], B0, z, 0, 0, 0);
            a1 = __builtin_amdgcn_mfma_f32_16x16x32_f16(A[1][1], B1, a1, 0, 0, 0);
            a2 = __builtin_amdgcn_mfma_f32_16x16x32_f16(A[2][1], B1, a2, 0, 0, 0);
            a3 = __builtin_amdgcn_mfma_f32_16x16x32_f16(A[3][1], B1, a3, 0, 0, 0);
        }

        const int idx = t + 1;
        const int nb  = idx & 1;

        // ---- wave 0: x slots of next buffer (rotate BEFORE read) ----
        if (wave == 0) {
            if ((idx & 3) == 0) {
                xq = xq2;
                int o = idx + 4; if (o > TT - 4) o = TT - 4;
                xq2 = *(const float4*)(xrow + o);
            }
            if (L15 < 4 && kq < 3) {
                const float xv = ((const float*)&xq)[idx & 3];
                const _Float16 xh = (_Float16)xv;
                const _Float16 xl = (_Float16)(xv - (float)xh);
                const int slot = (kq == 0) ? KX_HI : (kq == 1) ? KX_LO : KX_H2;
                hb[nb][L15][slot] = (kq == 1) ? xl : xh;
            }
        }

        // ---- select this lane's tile accumulator ----
        const f32x4 lo_  = (cp == 0) ? a0 : a1;
        const f32x4 hi_  = (cp == 2) ? a2 : a3;
        const f32x4 g4   = (cp < 2) ? lo_ : hi_;

        // ---- per-lane epilogue (gates pre-scaled/biased by the MFMA) ----
        const float i_ = __builtin_amdgcn_rcpf(1.0f + __builtin_amdgcn_exp2f(g4[0]));
        const float f_ = __builtin_amdgcn_rcpf(1.0f + __builtin_amdgcn_exp2f(g4[1]));
        const float g_ = __builtin_fmaf(-2.0f,
            __builtin_amdgcn_rcpf(1.0f + __builtin_amdgcn_exp2f(g4[2])), 1.0f);
        const float o_ = __builtin_amdgcn_rcpf(1.0f + __builtin_amdgcn_exp2f(g4[3]));
        c = __builtin_fmaf(f_, c, i_ * g_);
        const float tc_ = __builtin_fmaf(-2.0f,
            __builtin_amdgcn_rcpf(1.0f + __builtin_amdgcn_exp2f(LOG2E2 * c)), 1.0f);
        const float h = o_ * tc_;
        hlast = h;

        if (jv) hb[nb][bl][j] = (_Float16)h;   // single write, no copies
        __syncthreads();
    }

    // ---- head: out[b] = b_lin + sum_j W_lin[j] * h[j][b] ----
    if (jv) redH[j][bl] = wlin * hlast;
    __syncthreads();
    if (tid < BW) {
        float s = b_lin[0];
        #pragma unroll 10
        for (int jj = 0; jj < H; ++jj) s += redH[jj][tid];
        out[b0 + tid] = s;
    }
}

extern "C" void kernel_launch(void* const* d_in, const int* in_sizes, int n_in,
                              void* d_out, int out_size, void* d_ws, size_t ws_size,
                              hipStream_t stream) {
    const float* x     = (const float*)d_in[0];
    const float* W_ih  = (const float*)d_in[1];
    const float* W_hh  = (const float*)d_in[2];
    const float* b_ih  = (const float*)d_in[3];
    const float* b_hh  = (const float*)d_in[4];
    const float* W_lin = (const float*)d_in[5];
    const float* b_lin = (const float*)d_in[6];
    float* out = (float*)d_out;

    dim3 grid(BATCH / BW);    // 512 blocks, 2 per CU
    dim3 block(NTHR);         // 4 waves, 1 per SIMD
    lstm_kernel<<<grid, block, 0, stream>>>(x, W_ih, W_hh, b_ih, b_hh,
                                            W_lin, b_lin, out);
}

// Round 11
// 364.127 us; speedup vs baseline: 1.3441x; 1.3441x over previous
//
#include <hip/hip_runtime.h>

// LSTM B=2048, T=1024, H=50. Round 11: R9 frame + 7-trans fused epilogue +
// R10's conflict-free broadcast LDS layout (single h-write, no copies).
//
// grid=256 (1 block/CU — 2 blocks/CU phase-lock and serialize: R5/R10),
// block=448 = 7 waves, BW=8 batches.
// Wave w owns permuted gate-row tiles 2w, 2w+1 (rows n'=4j+g). Lane
// (kq, L15): pair (unit j = 8w + 4*(L15>>3) + kq, batch bl = L15&7); lanes
// L15 and L15+8 read the SAME hb row (free LDS broadcast, R10-measured).
// A = scaled W' single f16 in VGPRs (R9-validated):
//   i,f,o rows x -log2(e); g rows x +2log2(e) -> exp2-only activations.
//   K slots: 0-49 W_hh | 50-55 ZERO (pad-unit h lands here harmlessly)
//            56 wih_hi(B=x_hi) | 57 wih_hi(B=x_lo) | 58 wih_lo(B=x_hi)
//            59 bias_hi(B=1)   | 60 bias_lo(B=1)   | 61-63 zero.
// Epilogue (7 trans): Ei,Ef,Eg,Eo = exp2(gates); P=(1+Ei)(1+Eg); Q=1+Ef;
//   c' = (c*P + (Eg-1)*Q) * rcp(P*Q);  Ec = exp2(min(2log2e*c', 80));
//   h = (Ec-1) * rcp((1+Eo)(1+Ec)).     c-exp2 clamp kills inf*0 NaN.
// x slots written by waves 1/2/3 (one slot each, rows 0-7, next buffer).

#define H     50
#define TT    1024
#define BATCH 2048
#define BW    8
#define NTHR  448     // 7 waves
#define KP    80      // f16 per hb row: 40 words stride (R10-measured free)
#define KX_HI 56
#define KX_LO 57
#define KX_H2 58
#define KB_HI 59
#define KB_LO 60

typedef float    f32x4 __attribute__((ext_vector_type(4)));
typedef _Float16 f16x8 __attribute__((ext_vector_type(8)));

__global__ __launch_bounds__(NTHR, 1) void lstm_kernel(
    const float* __restrict__ x,      // [B, T]
    const float* __restrict__ W_ih,   // [200]
    const float* __restrict__ W_hh,   // [200, 50]
    const float* __restrict__ b_ih,   // [200]
    const float* __restrict__ b_hh,   // [200]
    const float* __restrict__ W_lin,  // [50]
    const float* __restrict__ b_lin,  // [1]
    float* __restrict__ out)          // [B]
{
    __shared__ _Float16 hb[2][BW][KP];   // h^T + x/bias slots, double-buffered
    __shared__ float    redH[H][BW];     // head reduction

    const int tid  = threadIdx.x;
    const int wave = tid >> 6;
    const int lane = tid & 63;
    const int L15  = lane & 15;
    const int kq   = lane >> 4;
    const int bl   = L15 & 7;            // batch of this lane
    const int b0   = blockIdx.x * BW;

    const int t0 = 2 * wave;             // tiles t0, t0+1 (wave 6: 12, 13=pad)

    const float LOG2E  = 1.4426950408889634f;
    const float LOG2E2 = 2.8853900817779268f;

    // ---- A fragments: scaled permuted W' rows, single f16, in VGPRs ----
    // tile tt: A[m=L15][k=kf*32+kq*8+e], global row m=16*(t0+tt)+L15 = 4j+g
    f16x8 A[2][2];
    #pragma unroll
    for (int tt = 0; tt < 2; ++tt) {
        const int m  = (t0 + tt) * 16 + L15;
        const int jm = m >> 2, gm = m & 3;
        const bool v = (jm < H);
        const float s = (gm == 2) ? LOG2E2 : -LOG2E;
        float swih = 0.f, sbias = 0.f;
        if (v) {
            swih  = s * W_ih[gm * H + jm];
            sbias = s * (b_ih[gm * H + jm] + b_hh[gm * H + jm]);
        }
        const _Float16 whi = (_Float16)swih;
        const _Float16 wlo = (_Float16)(swih - (float)whi);
        const _Float16 bhi = (_Float16)sbias;
        const _Float16 blo = (_Float16)(sbias - (float)bhi);
        #pragma unroll
        for (int kf = 0; kf < 2; ++kf) {
            f16x8 vv;
            #pragma unroll
            for (int e = 0; e < 8; ++e) {
                const int k = kf * 32 + kq * 8 + e;
                _Float16 val = (_Float16)0.f;
                if (v) {
                    if (k < H)            val = (_Float16)(s * W_hh[(gm * H + jm) * H + k]);
                    else if (k == KX_HI)  val = whi;
                    else if (k == KX_LO)  val = whi;
                    else if (k == KX_H2)  val = wlo;
                    else if (k == KB_HI)  val = bhi;
                    else if (k == KB_LO)  val = blo;
                    // k in 50..55, 61..63 stay 0: pad-unit h / zero pad.
                }
                vv[e] = val;
            }
            A[tt][kf] = vv;
        }
    }

    // ---- this lane's pair ----
    const int  j  = 8 * wave + ((L15 >> 3) << 2) + kq;   // 0..55 (50-55 pad)
    const bool jv = (j < H);
    const float wlin = jv ? W_lin[j] : 0.f;

    // ---- init LDS ----
    for (int i = tid; i < 2 * BW * KP; i += NTHR)
        ((_Float16*)hb)[i] = (_Float16)0.f;
    __syncthreads();
    if (tid < 16) {                       // ones slots, both buffers, 8 rows
        hb[tid >> 3][tid & 7][KB_HI] = (_Float16)1.0f;
        hb[tid >> 3][tid & 7][KB_LO] = (_Float16)1.0f;
    } else if (tid < 24) {                // x(t=0) slots, buffer 0
        const int bb = tid - 16;
        const float xv = x[(size_t)(b0 + bb) * TT];
        const _Float16 xh = (_Float16)xv;
        hb[0][bb][KX_HI] = xh;
        hb[0][bb][KX_LO] = (_Float16)(xv - (float)xh);
        hb[0][bb][KX_H2] = xh;
    }

    // ---- x prefetch: waves 1,2,3 each own one slot ----
    const float* xrow = x + (size_t)(b0 + bl) * TT;
    float4 xq = {0,0,0,0}, xq2 = {0,0,0,0};
    const bool xw = (wave >= 1 && wave <= 3);
    if (xw) {
        xq  = *(const float4*)(xrow);
        xq2 = *(const float4*)(xrow + 4);
    }
    const int xslot = (wave == 1) ? KX_HI : (wave == 2) ? KX_LO : KX_H2;

    float c = 0.f, hlast = 0.f;
    __syncthreads();

    for (int t = 0; t < TT; ++t) {
        // ---- B fragments: broadcast read of batch row bl (L15 & L15+8 same)
        const _Float16* hp = &hb[t & 1][bl][0];
        f16x8 B0 = *(const f16x8*)(hp + kq * 8);        // k 0..31
        f16x8 B1 = *(const f16x8*)(hp + 32 + kq * 8);   // k 32..63

        // ---- 4 MFMAs: two independent 2-deep chains ----
        const f32x4 z = {0.f, 0.f, 0.f, 0.f};
        f32x4 a0 = __builtin_amdgcn_mfma_f32_16x16x32_f16(A[0][0], B0, z, 0, 0, 0);
        f32x4 a1 = __builtin_amdgcn_mfma_f32_16x16x32_f16(A[1][0], B0, z, 0, 0, 0);
        a0 = __builtin_amdgcn_mfma_f32_16x16x32_f16(A[0][1], B1, a0, 0, 0, 0);
        a1 = __builtin_amdgcn_mfma_f32_16x16x32_f16(A[1][1], B1, a1, 0, 0, 0);

        const int idx = t + 1;
        const int nb  = idx & 1;

        // ---- waves 1-3: one x slot each of the next buffer ----
        if (xw) {
            if ((idx & 3) == 0) {
                xq = xq2;
                int o = idx + 4; if (o > TT - 4) o = TT - 4;
                xq2 = *(const float4*)(xrow + o);
            }
            if (L15 < 8 && kq == 0) {
                const float xv = ((const float*)&xq)[idx & 3];
                const _Float16 xh = (_Float16)xv;
                const _Float16 wv = (wave == 2) ? (_Float16)(xv - (float)xh) : xh;
                hb[nb][L15][xslot] = wv;
            }
        }

        // ---- select this lane's accumulator (tile t0 vs t0+1) ----
        const bool lo = (L15 < 8);
        const float gi = lo ? a0[0] : a1[0];
        const float gf = lo ? a0[1] : a1[1];
        const float gg = lo ? a0[2] : a1[2];
        const float go = lo ? a0[3] : a1[3];

        // ---- fused epilogue: 7 trans ----
        const float Ei = __builtin_amdgcn_exp2f(gi);
        const float Ef = __builtin_amdgcn_exp2f(gf);
        const float Eg = __builtin_amdgcn_exp2f(gg);
        const float Eo = __builtin_amdgcn_exp2f(go);
        const float P  = (1.0f + Ei) * (1.0f + Eg);
        const float Q  = 1.0f + Ef;
        const float num = __builtin_fmaf(c, P, (Eg - 1.0f) * Q);
        c = num * __builtin_amdgcn_rcpf(P * Q);
        const float ca = fminf(LOG2E2 * c, 80.0f);
        const float Ec = __builtin_amdgcn_exp2f(ca);
        const float h  = (Ec - 1.0f) *
            __builtin_amdgcn_rcpf((1.0f + Eo) * (1.0f + Ec));
        hlast = h;

        hb[nb][bl][j] = (_Float16)h;   // unguarded: pad j->zero-A slots 50-55
        __syncthreads();
    }

    // ---- head: out[b] = b_lin + sum_j W_lin[j] * h[j][b] ----
    if (jv && L15 < 8) redH[j][bl] = wlin * hlast;
    else if (jv)       redH[j][bl] = wlin * hlast;   // same value, same addr
    __syncthreads();
    if (tid < BW) {
        float s = b_lin[0];
        #pragma unroll 10
        for (int jj = 0; jj < H; ++jj) s += redH[jj][tid];
        out[b0 + tid] = s;
    }
}

extern "C" void kernel_launch(void* const* d_in, const int* in_sizes, int n_in,
                              void* d_out, int out_size, void* d_ws, size_t ws_size,
                              hipStream_t stream) {
    const float* x     = (const float*)d_in[0];
    const float* W_ih  = (const float*)d_in[1];
    const float* W_hh  = (const float*)d_in[2];
    const float* b_ih  = (const float*)d_in[3];
    const float* b_hh  = (const float*)d_in[4];
    const float* W_lin = (const float*)d_in[5];
    const float* b_lin = (const float*)d_in[6];
    float* out = (float*)d_out;

    dim3 grid(BATCH / BW);    // 256 blocks, 1 per CU
    dim3 block(NTHR);         // 7 waves
    lstm_kernel<<<grid, block, 0, stream>>>(x, W_ih, W_hh, b_ih, b_hh,
                                            W_lin, b_lin, out);
}